// Round 5
// baseline (85.320 us; speedup 1.0000x reference)
//
#include <hip/hip_runtime.h>
#include <hip/hip_bf16.h>

// out[e] = W2 . relu( u[row[e]] + v[col[e]] ) + b2
//   u[n] = (W1a@W_enc).seq[n] + (W1a.b_enc + b1)
//   v[n] = (W1b@W_enc).seq[n] +  W1b.b_enc
// UV table: [N_NODES][128] _Float16  (64 u | 64 v).
// Folded weight Wb: [128 out][128 k] bf16 (MFMA B operand), 32 KB = L1-sized.

#define K_IN  128
#define N_OUT 128

typedef short bf16x8 __attribute__((ext_vector_type(8)));
typedef float f32x4  __attribute__((ext_vector_type(4)));
typedef _Float16 half8 __attribute__((ext_vector_type(8)));
typedef int   i32x4 __attribute__((ext_vector_type(4)));
typedef float fv4   __attribute__((ext_vector_type(4)));

static __device__ __forceinline__ short f2bf(float x) {
    __hip_bfloat16 h = __float2bfloat16(x);
    return *reinterpret_cast<short*>(&h);
}

// ---------------- prep: fold weights into Wb[out][k] bf16 + bias ----------
__global__ __launch_bounds__(256) void prep_kernel(
        const float* __restrict__ W_enc, const float* __restrict__ b_enc,
        const float* __restrict__ W1,    const float* __restrict__ b1,
        __hip_bfloat16* __restrict__ Wb, float* __restrict__ bcat)
{
    int idx = blockIdx.x * blockDim.x + threadIdx.x;   // 0..16383
    if (idx >= N_OUT * K_IN) return;
    int i = idx >> 7;        // out 0..127 (0..63 = u, 64..127 = v)
    int k = idx & 127;       // in  0..127
    int irow = i & 63;
    int joff = (i < 64) ? 0 : 64;
    float s = 0.f;
    #pragma unroll 8
    for (int j = 0; j < 64; ++j)
        s = fmaf(W1[irow * 128 + joff + j], W_enc[j * 128 + k], s);
    Wb[i * K_IN + k] = __float2bfloat16(s);
    if (k == 0) {
        float b = 0.f;
        for (int j = 0; j < 64; ++j)
            b = fmaf(W1[irow * 128 + joff + j], b_enc[j], b);
        if (i < 64) b += b1[i];
        bcat[i] = b;
    }
}

// ---------------- node projection: UVh = bf16MFMA(seq, Wb) + bcat ---------
// 512 threads (8 waves), 128 nodes/block, K=128. No LDS, no barrier:
// A fragments straight from seq (coalesced float4), B fragments straight
// from Wb (32 KB, L1-resident). Waves free-run.
__global__ __launch_bounds__(512) void node_proj_kernel(
        const float* __restrict__ seq, const __hip_bfloat16* __restrict__ Wb,
        const float* __restrict__ bcat, _Float16* __restrict__ UVh, int nNodes)
{
    int tid  = threadIdx.x;
    int lane = tid & 63;
    int w    = tid >> 6;       // wave 0..7 -> node rows [16w, 16w+16)
    int lr   = lane & 15;
    int lg   = lane >> 4;
    int base = blockIdx.x * 128;

    int arow = base + 16 * w + lr;
    if (arow >= nNodes) arow = nNodes - 1;
    const float* aptr = seq + (size_t)arow * K_IN + lg * 8;
    const short* WbS  = (const short*)Wb;

    f32x4 acc[8];
    #pragma unroll
    for (int nt = 0; nt < 8; ++nt) {
        float b = bcat[nt * 16 + lr];
        acc[nt] = (f32x4){b, b, b, b};
    }

    #pragma unroll
    for (int kk = 0; kk < 4; ++kk) {
        float4 f0 = *(const float4*)(aptr + kk * 32);
        float4 f1 = *(const float4*)(aptr + kk * 32 + 4);
        bf16x8 a;
        a[0] = f2bf(f0.x); a[1] = f2bf(f0.y); a[2] = f2bf(f0.z); a[3] = f2bf(f0.w);
        a[4] = f2bf(f1.x); a[5] = f2bf(f1.y); a[6] = f2bf(f1.z); a[7] = f2bf(f1.w);
        #pragma unroll
        for (int nt = 0; nt < 8; ++nt) {
            bf16x8 b = *(const bf16x8*)(WbS + (nt * 16 + lr) * K_IN + kk * 32 + lg * 8);
            acc[nt] = __builtin_amdgcn_mfma_f32_16x16x32_bf16(a, b, acc[nt], 0, 0, 0);
        }
    }

    // store: D col = lane&15 (+16*nt), row = 4*lg + j  (m89/m91 mapping)
    int nodeb = base + 16 * w + lg * 4;
    #pragma unroll
    for (int j = 0; j < 4; ++j) {
        int node = nodeb + j;
        if (node < nNodes) {
            #pragma unroll
            for (int nt = 0; nt < 8; ++nt)
                UVh[(size_t)node * N_OUT + nt * 16 + lr] = (_Float16)acc[nt][j];
        }
    }
}

// ---------------- edge: 8 lanes/edge, x4 edge unroll, NT streaming --------
__global__ __launch_bounds__(256) void edge_kernel(
        const _Float16* __restrict__ UVh, const int* __restrict__ row,
        const int* __restrict__ col, const float* __restrict__ W2,
        const float* __restrict__ b2, float* __restrict__ out, int nEdges)
{
    int l = threadIdx.x & 7;
    float w2v[8];
    #pragma unroll
    for (int j = 0; j < 8; ++j) w2v[j] = W2[l * 8 + j];
    float bb = b2[0];

    int gid = (int)((blockIdx.x * blockDim.x + threadIdx.x) >> 3);
    int ng  = (int)((gridDim.x * blockDim.x) >> 3);

    for (int e0 = gid * 4; e0 < nEdges; e0 += ng * 4) {
        if (e0 + 4 <= nEdges) {
            i32x4 r4 = __builtin_nontemporal_load((const i32x4*)(row + e0));
            i32x4 c4 = __builtin_nontemporal_load((const i32x4*)(col + e0));
            // issue all 8 gathers before any compute
            half8 a0 = *(const half8*)(UVh + ((unsigned)r4[0] << 7) + l * 8);
            half8 b0 = *(const half8*)(UVh + ((unsigned)c4[0] << 7) + 64 + l * 8);
            half8 a1 = *(const half8*)(UVh + ((unsigned)r4[1] << 7) + l * 8);
            half8 b1 = *(const half8*)(UVh + ((unsigned)c4[1] << 7) + 64 + l * 8);
            half8 a2 = *(const half8*)(UVh + ((unsigned)r4[2] << 7) + l * 8);
            half8 b2v = *(const half8*)(UVh + ((unsigned)c4[2] << 7) + 64 + l * 8);
            half8 a3 = *(const half8*)(UVh + ((unsigned)r4[3] << 7) + l * 8);
            half8 b3 = *(const half8*)(UVh + ((unsigned)c4[3] << 7) + 64 + l * 8);

            float p0 = 0.f, p1 = 0.f, p2 = 0.f, p3 = 0.f;
            #pragma unroll
            for (int j = 0; j < 8; ++j) {
                p0 = fmaf(fmaxf((float)a0[j] + (float)b0[j], 0.f), w2v[j], p0);
                p1 = fmaf(fmaxf((float)a1[j] + (float)b1[j], 0.f), w2v[j], p1);
                p2 = fmaf(fmaxf((float)a2[j] + (float)b2v[j], 0.f), w2v[j], p2);
                p3 = fmaf(fmaxf((float)a3[j] + (float)b3[j], 0.f), w2v[j], p3);
            }
            #pragma unroll
            for (int s = 1; s < 8; s <<= 1) {
                p0 += __shfl_xor(p0, s);
                p1 += __shfl_xor(p1, s);
                p2 += __shfl_xor(p2, s);
                p3 += __shfl_xor(p3, s);
            }
            if (l == 0) {
                fv4 o = {p0 + bb, p1 + bb, p2 + bb, p3 + bb};
                __builtin_nontemporal_store(o, (fv4*)(out + e0));
            }
        } else {
            for (int e = e0; e < nEdges; ++e) {
                int r = row[e];
                int c = col[e];
                half8 a = *(const half8*)(UVh + ((unsigned)r << 7) + l * 8);
                half8 b = *(const half8*)(UVh + ((unsigned)c << 7) + 64 + l * 8);
                float p = 0.f;
                #pragma unroll
                for (int j = 0; j < 8; ++j)
                    p = fmaf(fmaxf((float)a[j] + (float)b[j], 0.f), w2v[j], p);
                #pragma unroll
                for (int s = 1; s < 8; s <<= 1) p += __shfl_xor(p, s);
                if (l == 0) out[e] = p + bb;
            }
        }
    }
}

extern "C" void kernel_launch(void* const* d_in, const int* in_sizes, int n_in,
                              void* d_out, int out_size, void* d_ws, size_t ws_size,
                              hipStream_t stream) {
    const float* seq   = (const float*)d_in[0];
    const float* W_enc = (const float*)d_in[1];
    const float* b_enc = (const float*)d_in[2];
    const float* W1    = (const float*)d_in[3];
    const float* b1    = (const float*)d_in[4];
    const float* W2    = (const float*)d_in[5];
    const float* b2    = (const float*)d_in[6];
    const int*   row   = (const int*)d_in[7];
    const int*   col   = (const int*)d_in[8];
    float* out = (float*)d_out;

    int nNodes = in_sizes[0] / K_IN;     // 100000
    int nEdges = in_sizes[7];            // 1000000

    // workspace layout
    _Float16* UVh = (_Float16*)d_ws;                                   // 25.6 MB
    __hip_bfloat16* Wb = (__hip_bfloat16*)((char*)d_ws +
                         (size_t)nNodes * N_OUT * sizeof(_Float16));   // 32 KB
    float* bcat = (float*)((char*)Wb + N_OUT * K_IN * sizeof(__hip_bfloat16));

    prep_kernel<<<(N_OUT * K_IN + 255) / 256, 256, 0, stream>>>(
        W_enc, b_enc, W1, b1, Wb, bcat);

    int nblocksA = (nNodes + 127) / 128;
    node_proj_kernel<<<nblocksA, 512, 0, stream>>>(seq, Wb, bcat, UVh, nNodes);

    edge_kernel<<<2048, 256, 0, stream>>>(UVh, row, col, W2, b2, out, nEdges);
}

// Round 6
// 61.938 us; speedup vs baseline: 1.3775x; 1.3775x over previous
//
#include <hip/hip_runtime.h>
#include <hip/hip_bf16.h>

// out[e] = W2 . relu( u[row[e]] + v[col[e]] ) + b2
//   u[n] = (W1a@W_enc).seq[n] + (W1a.b_enc + b1)
//   v[n] = (W1b@W_enc).seq[n] +  W1b.b_enc
// UV table: [N_NODES][128] _Float16  (64 u | 64 v).
// Folded weight Wb: [128 out][128 k] bf16 (MFMA B operand).

#define K_IN  128
#define N_OUT 128
#define LDB   136   // 128 + 8 bf16 pad

typedef short bf16x8 __attribute__((ext_vector_type(8)));
typedef float f32x4  __attribute__((ext_vector_type(4)));
typedef _Float16 half8 __attribute__((ext_vector_type(8)));
typedef int   i32x4 __attribute__((ext_vector_type(4)));
typedef float fv4   __attribute__((ext_vector_type(4)));

static __device__ __forceinline__ short f2bf(float x) {
    __hip_bfloat16 h = __float2bfloat16(x);
    return *reinterpret_cast<short*>(&h);
}

// ---------------- prep: fold weights into Wb[out][k] bf16 + bias ----------
__global__ __launch_bounds__(256) void prep_kernel(
        const float* __restrict__ W_enc, const float* __restrict__ b_enc,
        const float* __restrict__ W1,    const float* __restrict__ b1,
        __hip_bfloat16* __restrict__ Wb, float* __restrict__ bcat)
{
    int idx = blockIdx.x * blockDim.x + threadIdx.x;   // 0..16383
    if (idx >= N_OUT * K_IN) return;
    int i = idx >> 7;        // out 0..127 (0..63 = u, 64..127 = v)
    int k = idx & 127;       // in  0..127
    int irow = i & 63;
    int joff = (i < 64) ? 0 : 64;
    float s = 0.f;
    #pragma unroll 8
    for (int j = 0; j < 64; ++j)
        s = fmaf(W1[irow * 128 + joff + j], W_enc[j * 128 + k], s);
    Wb[i * K_IN + k] = __float2bfloat16(s);
    if (k == 0) {
        float b = 0.f;
        for (int j = 0; j < 64; ++j)
            b = fmaf(W1[irow * 128 + joff + j], b_enc[j], b);
        if (i < 64) b += b1[i];
        bcat[i] = b;
    }
}

// ---------------- node projection: UVh = bf16MFMA(seq, Wb) + bcat ---------
// 256 threads (4 waves), 128 nodes/block. B staged once in LDS (32 KB),
// each wave owns TWO 16-row blocks so every B ds_read feeds 2 MFMAs.
// A fragments direct from global (coalesced float4, 4 lg-lanes = 128 B/row).
__global__ __launch_bounds__(256) void node_proj_kernel(
        const float* __restrict__ seq, const __hip_bfloat16* __restrict__ Wb,
        const float* __restrict__ bcat, _Float16* __restrict__ UVh, int nNodes)
{
    __shared__ short Bs[N_OUT * LDB];

    int tid  = threadIdx.x;
    int base = blockIdx.x * 128;

    // stage B: Wb [128][128] bf16 -> LDS (16B chunks, coalesced)
    #pragma unroll
    for (int it = 0; it < 8; ++it) {
        int c8 = tid + 256 * it;            // 8-elem chunk 0..2047
        int r  = c8 >> 4;                   // out row 0..127
        int cb = (c8 & 15) * 8;             // k 0..120
        *(int4*)(Bs + r * LDB + cb) = *(const int4*)(Wb + r * K_IN + cb);
    }
    __syncthreads();

    int lane = tid & 63;
    int w    = tid >> 6;       // wave 0..3 -> node rows [32w, 32w+32)
    int lr   = lane & 15;
    int lg   = lane >> 4;

    int arow0 = base + 32 * w + lr;        // row-block m=0
    int arow1 = arow0 + 16;                // row-block m=1
    if (arow0 >= nNodes) arow0 = nNodes - 1;
    if (arow1 >= nNodes) arow1 = nNodes - 1;
    const float* ap0 = seq + (size_t)arow0 * K_IN + lg * 8;
    const float* ap1 = seq + (size_t)arow1 * K_IN + lg * 8;

    f32x4 acc0[8], acc1[8];
    #pragma unroll
    for (int nt = 0; nt < 8; ++nt) {
        float b = bcat[nt * 16 + lr];
        acc0[nt] = (f32x4){b, b, b, b};
        acc1[nt] = (f32x4){b, b, b, b};
    }

    #pragma unroll
    for (int kk = 0; kk < 4; ++kk) {
        float4 f0 = *(const float4*)(ap0 + kk * 32);
        float4 f1 = *(const float4*)(ap0 + kk * 32 + 4);
        float4 g0 = *(const float4*)(ap1 + kk * 32);
        float4 g1 = *(const float4*)(ap1 + kk * 32 + 4);
        bf16x8 a0, a1;
        a0[0] = f2bf(f0.x); a0[1] = f2bf(f0.y); a0[2] = f2bf(f0.z); a0[3] = f2bf(f0.w);
        a0[4] = f2bf(f1.x); a0[5] = f2bf(f1.y); a0[6] = f2bf(f1.z); a0[7] = f2bf(f1.w);
        a1[0] = f2bf(g0.x); a1[1] = f2bf(g0.y); a1[2] = f2bf(g0.z); a1[3] = f2bf(g0.w);
        a1[4] = f2bf(g1.x); a1[5] = f2bf(g1.y); a1[6] = f2bf(g1.z); a1[7] = f2bf(g1.w);
        #pragma unroll
        for (int nt = 0; nt < 8; ++nt) {
            bf16x8 b = *(bf16x8*)(Bs + (nt * 16 + lr) * LDB + kk * 32 + lg * 8);
            acc0[nt] = __builtin_amdgcn_mfma_f32_16x16x32_bf16(a0, b, acc0[nt], 0, 0, 0);
            acc1[nt] = __builtin_amdgcn_mfma_f32_16x16x32_bf16(a1, b, acc1[nt], 0, 0, 0);
        }
    }

    // store: D col = lane&15 (+16*nt), row = 4*lg + j  (m89/m91 mapping)
    #pragma unroll
    for (int m = 0; m < 2; ++m) {
        int nodeb = base + 32 * w + 16 * m + lg * 4;
        #pragma unroll
        for (int j = 0; j < 4; ++j) {
            int node = nodeb + j;
            if (node < nNodes) {
                #pragma unroll
                for (int nt = 0; nt < 8; ++nt) {
                    f32x4 acc = m ? acc1[nt] : acc0[nt];
                    UVh[(size_t)node * N_OUT + nt * 16 + lr] = (_Float16)acc[j];
                }
            }
        }
    }
}

// ---------------- edge: 8 lanes/edge, x4 edge unroll, NT streaming --------
__global__ __launch_bounds__(256) void edge_kernel(
        const _Float16* __restrict__ UVh, const int* __restrict__ row,
        const int* __restrict__ col, const float* __restrict__ W2,
        const float* __restrict__ b2, float* __restrict__ out, int nEdges)
{
    int l = threadIdx.x & 7;
    float w2v[8];
    #pragma unroll
    for (int j = 0; j < 8; ++j) w2v[j] = W2[l * 8 + j];
    float bb = b2[0];

    int gid = (int)((blockIdx.x * blockDim.x + threadIdx.x) >> 3);
    int ng  = (int)((gridDim.x * blockDim.x) >> 3);

    for (int e0 = gid * 4; e0 < nEdges; e0 += ng * 4) {
        if (e0 + 4 <= nEdges) {
            i32x4 r4 = __builtin_nontemporal_load((const i32x4*)(row + e0));
            i32x4 c4 = __builtin_nontemporal_load((const i32x4*)(col + e0));
            // issue all 8 gathers before any compute
            half8 a0 = *(const half8*)(UVh + ((unsigned)r4[0] << 7) + l * 8);
            half8 b0 = *(const half8*)(UVh + ((unsigned)c4[0] << 7) + 64 + l * 8);
            half8 a1 = *(const half8*)(UVh + ((unsigned)r4[1] << 7) + l * 8);
            half8 b1 = *(const half8*)(UVh + ((unsigned)c4[1] << 7) + 64 + l * 8);
            half8 a2 = *(const half8*)(UVh + ((unsigned)r4[2] << 7) + l * 8);
            half8 b2v = *(const half8*)(UVh + ((unsigned)c4[2] << 7) + 64 + l * 8);
            half8 a3 = *(const half8*)(UVh + ((unsigned)r4[3] << 7) + l * 8);
            half8 b3 = *(const half8*)(UVh + ((unsigned)c4[3] << 7) + 64 + l * 8);

            float p0 = 0.f, p1 = 0.f, p2 = 0.f, p3 = 0.f;
            #pragma unroll
            for (int j = 0; j < 8; ++j) {
                p0 = fmaf(fmaxf((float)a0[j] + (float)b0[j], 0.f), w2v[j], p0);
                p1 = fmaf(fmaxf((float)a1[j] + (float)b1[j], 0.f), w2v[j], p1);
                p2 = fmaf(fmaxf((float)a2[j] + (float)b2v[j], 0.f), w2v[j], p2);
                p3 = fmaf(fmaxf((float)a3[j] + (float)b3[j], 0.f), w2v[j], p3);
            }
            #pragma unroll
            for (int s = 1; s < 8; s <<= 1) {
                p0 += __shfl_xor(p0, s);
                p1 += __shfl_xor(p1, s);
                p2 += __shfl_xor(p2, s);
                p3 += __shfl_xor(p3, s);
            }
            if (l == 0) {
                fv4 o = {p0 + bb, p1 + bb, p2 + bb, p3 + bb};
                __builtin_nontemporal_store(o, (fv4*)(out + e0));
            }
        } else {
            for (int e = e0; e < nEdges; ++e) {
                int r = row[e];
                int c = col[e];
                half8 a = *(const half8*)(UVh + ((unsigned)r << 7) + l * 8);
                half8 b = *(const half8*)(UVh + ((unsigned)c << 7) + 64 + l * 8);
                float p = 0.f;
                #pragma unroll
                for (int j = 0; j < 8; ++j)
                    p = fmaf(fmaxf((float)a[j] + (float)b[j], 0.f), w2v[j], p);
                #pragma unroll
                for (int s = 1; s < 8; s <<= 1) p += __shfl_xor(p, s);
                if (l == 0) out[e] = p + bb;
            }
        }
    }
}

extern "C" void kernel_launch(void* const* d_in, const int* in_sizes, int n_in,
                              void* d_out, int out_size, void* d_ws, size_t ws_size,
                              hipStream_t stream) {
    const float* seq   = (const float*)d_in[0];
    const float* W_enc = (const float*)d_in[1];
    const float* b_enc = (const float*)d_in[2];
    const float* W1    = (const float*)d_in[3];
    const float* b1    = (const float*)d_in[4];
    const float* W2    = (const float*)d_in[5];
    const float* b2    = (const float*)d_in[6];
    const int*   row   = (const int*)d_in[7];
    const int*   col   = (const int*)d_in[8];
    float* out = (float*)d_out;

    int nNodes = in_sizes[0] / K_IN;     // 100000
    int nEdges = in_sizes[7];            // 1000000

    // workspace layout
    _Float16* UVh = (_Float16*)d_ws;                                   // 25.6 MB
    __hip_bfloat16* Wb = (__hip_bfloat16*)((char*)d_ws +
                         (size_t)nNodes * N_OUT * sizeof(_Float16));   // 32 KB
    float* bcat = (float*)((char*)Wb + N_OUT * K_IN * sizeof(__hip_bfloat16));

    prep_kernel<<<(N_OUT * K_IN + 255) / 256, 256, 0, stream>>>(
        W_enc, b_enc, W1, b1, Wb, bcat);

    int nblocksA = (nNodes + 127) / 128;
    node_proj_kernel<<<nblocksA, 256, 0, stream>>>(seq, Wb, bcat, UVh, nNodes);

    edge_kernel<<<2048, 256, 0, stream>>>(UVh, row, col, W2, b2, out, nEdges);
}

// Round 7
// 60.047 us; speedup vs baseline: 1.4209x; 1.0315x over previous
//
#include <hip/hip_runtime.h>
#include <hip/hip_bf16.h>

// out[e] = W2 . relu( u[row[e]] + v[col[e]] ) + b2
//   u[n] = (W1a@W_enc).seq[n] + (W1a.b_enc + b1)
//   v[n] = (W1b@W_enc).seq[n] +  W1b.b_enc
// UV table: [N_NODES][128] _Float16, PERMUTED within each 64-half:
//   storage pos p = lr*4 + nt  <->  hidden unit i = (p&3)*16 + (p>>2)
// (same permutation for u and v halves, so u_i+v_i stays aligned; edge
//  kernel reads W2 through the inverse permutation).
// Folded weight Wb: [128 out][128 k] bf16 (MFMA B operand).

#define K_IN  128
#define N_OUT 128
#define LDB   136   // 128 + 8 bf16 pad

typedef short bf16x8 __attribute__((ext_vector_type(8)));
typedef float f32x4  __attribute__((ext_vector_type(4)));
typedef _Float16 half8 __attribute__((ext_vector_type(8)));
typedef _Float16 half4v __attribute__((ext_vector_type(4)));
typedef float fv4   __attribute__((ext_vector_type(4)));

static __device__ __forceinline__ short f2bf(float x) {
    __hip_bfloat16 h = __float2bfloat16(x);
    return *reinterpret_cast<short*>(&h);
}

// ---------------- prep: fold weights into Wb[out][k] bf16 + bias ----------
__global__ __launch_bounds__(256) void prep_kernel(
        const float* __restrict__ W_enc, const float* __restrict__ b_enc,
        const float* __restrict__ W1,    const float* __restrict__ b1,
        __hip_bfloat16* __restrict__ Wb, float* __restrict__ bcat)
{
    int idx = blockIdx.x * blockDim.x + threadIdx.x;   // 0..16383
    if (idx >= N_OUT * K_IN) return;
    int i = idx >> 7;        // out 0..127 (0..63 = u, 64..127 = v)
    int k = idx & 127;       // in  0..127
    int irow = i & 63;
    int joff = (i < 64) ? 0 : 64;
    float s = 0.f;
    #pragma unroll 8
    for (int j = 0; j < 64; ++j)
        s = fmaf(W1[irow * 128 + joff + j], W_enc[j * 128 + k], s);
    Wb[i * K_IN + k] = __float2bfloat16(s);
    if (k == 0) {
        float b = 0.f;
        for (int j = 0; j < 64; ++j)
            b = fmaf(W1[irow * 128 + joff + j], b_enc[j], b);
        if (i < 64) b += b1[i];
        bcat[i] = b;
    }
}

// ---------------- node projection: UVh = bf16MFMA(seq, Wb) + bcat ---------
// 256 threads (4 waves), grid-stride over 64-node tiles (B staged once per
// block, reused across tiles). A direct from global (coalesced float4).
// Epilogue: permuted layout -> two coalesced half4 stores per node per lane.
__global__ __launch_bounds__(256) void node_proj_kernel(
        const float* __restrict__ seq, const __hip_bfloat16* __restrict__ Wb,
        const float* __restrict__ bcat, _Float16* __restrict__ UVh,
        int nNodes, int nTiles)
{
    __shared__ short Bs[N_OUT * LDB];

    int tid = threadIdx.x;

    // stage B: Wb [128][128] bf16 -> LDS (16B chunks, coalesced)
    #pragma unroll
    for (int it = 0; it < 8; ++it) {
        int c8 = tid + 256 * it;            // 8-elem chunk 0..2047
        int r  = c8 >> 4;                   // out row 0..127
        int cb = (c8 & 15) * 8;             // k 0..120
        *(int4*)(Bs + r * LDB + cb) = *(const int4*)(Wb + r * K_IN + cb);
    }
    __syncthreads();

    int lane = tid & 63;
    int w    = tid >> 6;       // wave 0..3 -> node rows [16w, 16w+16)
    int lr   = lane & 15;
    int lg   = lane >> 4;

    float bias[8];
    #pragma unroll
    for (int nt = 0; nt < 8; ++nt) bias[nt] = bcat[nt * 16 + lr];

    for (int tile = blockIdx.x; tile < nTiles; tile += gridDim.x) {
        int base = tile * 64;
        int arow = base + 16 * w + lr;
        if (arow >= nNodes) arow = nNodes - 1;
        const float* aptr = seq + (size_t)arow * K_IN + lg * 8;

        f32x4 acc[8];
        #pragma unroll
        for (int nt = 0; nt < 8; ++nt)
            acc[nt] = (f32x4){bias[nt], bias[nt], bias[nt], bias[nt]};

        #pragma unroll
        for (int kk = 0; kk < 4; ++kk) {
            float4 f0 = *(const float4*)(aptr + kk * 32);
            float4 f1 = *(const float4*)(aptr + kk * 32 + 4);
            bf16x8 a;
            a[0] = f2bf(f0.x); a[1] = f2bf(f0.y); a[2] = f2bf(f0.z); a[3] = f2bf(f0.w);
            a[4] = f2bf(f1.x); a[5] = f2bf(f1.y); a[6] = f2bf(f1.z); a[7] = f2bf(f1.w);
            #pragma unroll
            for (int nt = 0; nt < 8; ++nt) {
                bf16x8 b = *(bf16x8*)(Bs + (nt * 16 + lr) * LDB + kk * 32 + lg * 8);
                acc[nt] = __builtin_amdgcn_mfma_f32_16x16x32_bf16(a, b, acc[nt], 0, 0, 0);
            }
        }

        // D: col i = nt*16+lr, node row = 4*lg + j. Permuted store:
        // u-half pos = lr*4+nt (nt 0..3), v-half pos = 64 + lr*4 + (nt-4).
        int nodeb = base + 16 * w + lg * 4;
        #pragma unroll
        for (int j = 0; j < 4; ++j) {
            int node = nodeb + j;
            if (node < nNodes) {
                half4v u = {(_Float16)acc[0][j], (_Float16)acc[1][j],
                            (_Float16)acc[2][j], (_Float16)acc[3][j]};
                half4v v = {(_Float16)acc[4][j], (_Float16)acc[5][j],
                            (_Float16)acc[6][j], (_Float16)acc[7][j]};
                *(half4v*)(UVh + (size_t)node * N_OUT + lr * 4)      = u;
                *(half4v*)(UVh + (size_t)node * N_OUT + 64 + lr * 4) = v;
            }
        }
    }
}

// ---------------- edge: 8 lanes/edge, x4 edge unroll -----------------------
// W2 read through the inverse permutation: pos p -> hidden i = (p&3)*16+(p>>2)
__global__ __launch_bounds__(256) void edge_kernel(
        const _Float16* __restrict__ UVh, const int* __restrict__ row,
        const int* __restrict__ col, const float* __restrict__ W2,
        const float* __restrict__ b2, float* __restrict__ out, int nEdges)
{
    int l = threadIdx.x & 7;
    float w2v[8];
    #pragma unroll
    for (int j = 0; j < 8; ++j) {
        int p = l * 8 + j;                       // storage position 0..63
        w2v[j] = W2[(p & 3) * 16 + (p >> 2)];    // hidden unit index
    }
    float bb = b2[0];

    int gid = (int)((blockIdx.x * blockDim.x + threadIdx.x) >> 3);
    int ng  = (int)((gridDim.x * blockDim.x) >> 3);

    for (int e0 = gid * 4; e0 < nEdges; e0 += ng * 4) {
        if (e0 + 4 <= nEdges) {
            int4 r4 = *(const int4*)(row + e0);
            int4 c4 = *(const int4*)(col + e0);
            // issue all 8 gathers before any compute
            half8 a0 = *(const half8*)(UVh + ((unsigned)r4.x << 7) + l * 8);
            half8 b0 = *(const half8*)(UVh + ((unsigned)c4.x << 7) + 64 + l * 8);
            half8 a1 = *(const half8*)(UVh + ((unsigned)r4.y << 7) + l * 8);
            half8 b1 = *(const half8*)(UVh + ((unsigned)c4.y << 7) + 64 + l * 8);
            half8 a2 = *(const half8*)(UVh + ((unsigned)r4.z << 7) + l * 8);
            half8 b2v = *(const half8*)(UVh + ((unsigned)c4.z << 7) + 64 + l * 8);
            half8 a3 = *(const half8*)(UVh + ((unsigned)r4.w << 7) + l * 8);
            half8 b3 = *(const half8*)(UVh + ((unsigned)c4.w << 7) + 64 + l * 8);

            float p0 = 0.f, p1 = 0.f, p2 = 0.f, p3 = 0.f;
            #pragma unroll
            for (int j = 0; j < 8; ++j) {
                p0 = fmaf(fmaxf((float)a0[j] + (float)b0[j], 0.f), w2v[j], p0);
                p1 = fmaf(fmaxf((float)a1[j] + (float)b1[j], 0.f), w2v[j], p1);
                p2 = fmaf(fmaxf((float)a2[j] + (float)b2v[j], 0.f), w2v[j], p2);
                p3 = fmaf(fmaxf((float)a3[j] + (float)b3[j], 0.f), w2v[j], p3);
            }
            #pragma unroll
            for (int s = 1; s < 8; s <<= 1) {
                p0 += __shfl_xor(p0, s);
                p1 += __shfl_xor(p1, s);
                p2 += __shfl_xor(p2, s);
                p3 += __shfl_xor(p3, s);
            }
            if (l == 0) {
                fv4 o = {p0 + bb, p1 + bb, p2 + bb, p3 + bb};
                __builtin_nontemporal_store(o, (fv4*)(out + e0));
            }
        } else {
            for (int e = e0; e < nEdges; ++e) {
                int r = row[e];
                int c = col[e];
                half8 a = *(const half8*)(UVh + ((unsigned)r << 7) + l * 8);
                half8 b = *(const half8*)(UVh + ((unsigned)c << 7) + 64 + l * 8);
                float p = 0.f;
                #pragma unroll
                for (int j = 0; j < 8; ++j)
                    p = fmaf(fmaxf((float)a[j] + (float)b[j], 0.f), w2v[j], p);
                #pragma unroll
                for (int s = 1; s < 8; s <<= 1) p += __shfl_xor(p, s);
                if (l == 0) out[e] = p + bb;
            }
        }
    }
}

extern "C" void kernel_launch(void* const* d_in, const int* in_sizes, int n_in,
                              void* d_out, int out_size, void* d_ws, size_t ws_size,
                              hipStream_t stream) {
    const float* seq   = (const float*)d_in[0];
    const float* W_enc = (const float*)d_in[1];
    const float* b_enc = (const float*)d_in[2];
    const float* W1    = (const float*)d_in[3];
    const float* b1    = (const float*)d_in[4];
    const float* W2    = (const float*)d_in[5];
    const float* b2    = (const float*)d_in[6];
    const int*   row   = (const int*)d_in[7];
    const int*   col   = (const int*)d_in[8];
    float* out = (float*)d_out;

    int nNodes = in_sizes[0] / K_IN;     // 100000
    int nEdges = in_sizes[7];            // 1000000

    // workspace layout
    _Float16* UVh = (_Float16*)d_ws;                                   // 25.6 MB
    __hip_bfloat16* Wb = (__hip_bfloat16*)((char*)d_ws +
                         (size_t)nNodes * N_OUT * sizeof(_Float16));   // 32 KB
    float* bcat = (float*)((char*)Wb + N_OUT * K_IN * sizeof(__hip_bfloat16));

    prep_kernel<<<(N_OUT * K_IN + 255) / 256, 256, 0, stream>>>(
        W_enc, b_enc, W1, b1, Wb, bcat);

    int nTiles = (nNodes + 63) / 64;                 // 1563
    int nblocksA = (nTiles + 1) / 2;                 // 2 tiles per block
    node_proj_kernel<<<nblocksA, 256, 0, stream>>>(seq, Wb, bcat, UVh, nNodes, nTiles);

    edge_kernel<<<2048, 256, 0, stream>>>(UVh, row, col, W2, b2, out, nEdges);
}

// Round 8
// 58.257 us; speedup vs baseline: 1.4645x; 1.0307x over previous
//
#include <hip/hip_runtime.h>
#include <hip/hip_bf16.h>

// out[e] = W2 . relu( u[row[e]] + v[col[e]] ) + b2
//   u[n] = (W1a@W_enc).seq[n] + (W1a.b_enc + b1)
//   v[n] = (W1b@W_enc).seq[n] +  W1b.b_enc
// UV table: [N_NODES][128] _Float16, PERMUTED within each 64-half:
//   storage pos p = lr*4 + nt  <->  hidden unit i = (p&3)*16 + (p>>2)
// Folded weight Wb: [128 out][128 k] bf16 (MFMA B operand).

#define K_IN  128
#define N_OUT 128
#define LDB   136   // 128 + 8 bf16 pad

typedef short bf16x8 __attribute__((ext_vector_type(8)));
typedef float f32x4  __attribute__((ext_vector_type(4)));
typedef _Float16 half8 __attribute__((ext_vector_type(8)));
typedef _Float16 half4v __attribute__((ext_vector_type(4)));
typedef float fv4   __attribute__((ext_vector_type(4)));

static __device__ __forceinline__ short f2bf(float x) {
    __hip_bfloat16 h = __float2bfloat16(x);
    return *reinterpret_cast<short*>(&h);
}

// ---------------- prep: fold weights into Wb[out][k] bf16 + bias ----------
__global__ __launch_bounds__(256) void prep_kernel(
        const float* __restrict__ W_enc, const float* __restrict__ b_enc,
        const float* __restrict__ W1,    const float* __restrict__ b1,
        __hip_bfloat16* __restrict__ Wb, float* __restrict__ bcat)
{
    int idx = blockIdx.x * blockDim.x + threadIdx.x;   // 0..16383
    if (idx >= N_OUT * K_IN) return;
    int i = idx >> 7;        // out 0..127 (0..63 = u, 64..127 = v)
    int k = idx & 127;       // in  0..127
    int irow = i & 63;
    int joff = (i < 64) ? 0 : 64;
    float s = 0.f;
    #pragma unroll 8
    for (int j = 0; j < 64; ++j)
        s = fmaf(W1[irow * 128 + joff + j], W_enc[j * 128 + k], s);
    Wb[i * K_IN + k] = __float2bfloat16(s);
    if (k == 0) {
        float b = 0.f;
        for (int j = 0; j < 64; ++j)
            b = fmaf(W1[irow * 128 + joff + j], b_enc[j], b);
        if (i < 64) b += b1[i];
        bcat[i] = b;
    }
}

// ---------------- node projection: UVh = bf16MFMA(seq, Wb) + bcat ---------
// 512 threads (8 waves), 128 nodes/block, B staged once in LDS (34 KB).
// 4 blocks/CU x 8 waves = 32 waves/CU (100% occupancy) to maximize
// outstanding seq reads. A direct from global (coalesced float4).
__global__ __launch_bounds__(512) void node_proj_kernel(
        const float* __restrict__ seq, const __hip_bfloat16* __restrict__ Wb,
        const float* __restrict__ bcat, _Float16* __restrict__ UVh, int nNodes)
{
    __shared__ short Bs[N_OUT * LDB];

    int tid = threadIdx.x;

    // stage B: Wb [128][128] bf16 -> LDS (16B chunks, coalesced)
    #pragma unroll
    for (int it = 0; it < 4; ++it) {
        int c8 = tid + 512 * it;            // 8-elem chunk 0..2047
        int r  = c8 >> 4;                   // out row 0..127
        int cb = (c8 & 15) * 8;             // k 0..120
        *(int4*)(Bs + r * LDB + cb) = *(const int4*)(Wb + r * K_IN + cb);
    }
    __syncthreads();

    int lane = tid & 63;
    int w    = tid >> 6;       // wave 0..7 -> node rows [16w, 16w+16)
    int lr   = lane & 15;
    int lg   = lane >> 4;
    int base = blockIdx.x * 128;

    int arow = base + 16 * w + lr;
    if (arow >= nNodes) arow = nNodes - 1;
    const float* aptr = seq + (size_t)arow * K_IN + lg * 8;

    f32x4 acc[8];
    #pragma unroll
    for (int nt = 0; nt < 8; ++nt) {
        float b = bcat[nt * 16 + lr];
        acc[nt] = (f32x4){b, b, b, b};
    }

    #pragma unroll
    for (int kk = 0; kk < 4; ++kk) {
        float4 f0 = *(const float4*)(aptr + kk * 32);
        float4 f1 = *(const float4*)(aptr + kk * 32 + 4);
        bf16x8 a;
        a[0] = f2bf(f0.x); a[1] = f2bf(f0.y); a[2] = f2bf(f0.z); a[3] = f2bf(f0.w);
        a[4] = f2bf(f1.x); a[5] = f2bf(f1.y); a[6] = f2bf(f1.z); a[7] = f2bf(f1.w);
        #pragma unroll
        for (int nt = 0; nt < 8; ++nt) {
            bf16x8 b = *(bf16x8*)(Bs + (nt * 16 + lr) * LDB + kk * 32 + lg * 8);
            acc[nt] = __builtin_amdgcn_mfma_f32_16x16x32_bf16(a, b, acc[nt], 0, 0, 0);
        }
    }

    // D: col i = nt*16+lr, node row = 4*lg + j. Permuted store:
    // u-half pos = lr*4+nt (nt 0..3), v-half pos = 64 + lr*4 + (nt-4).
    int nodeb = base + 16 * w + lg * 4;
    #pragma unroll
    for (int j = 0; j < 4; ++j) {
        int node = nodeb + j;
        if (node < nNodes) {
            half4v u = {(_Float16)acc[0][j], (_Float16)acc[1][j],
                        (_Float16)acc[2][j], (_Float16)acc[3][j]};
            half4v v = {(_Float16)acc[4][j], (_Float16)acc[5][j],
                        (_Float16)acc[6][j], (_Float16)acc[7][j]};
            *(half4v*)(UVh + (size_t)node * N_OUT + lr * 4)      = u;
            *(half4v*)(UVh + (size_t)node * N_OUT + 64 + lr * 4) = v;
        }
    }
}

// ---------------- edge: 8 lanes/edge, x4 edge unroll -----------------------
// W2 read through the inverse permutation: pos p -> hidden i = (p&3)*16+(p>>2)
__global__ __launch_bounds__(256) void edge_kernel(
        const _Float16* __restrict__ UVh, const int* __restrict__ row,
        const int* __restrict__ col, const float* __restrict__ W2,
        const float* __restrict__ b2, float* __restrict__ out, int nEdges)
{
    int l = threadIdx.x & 7;
    float w2v[8];
    #pragma unroll
    for (int j = 0; j < 8; ++j) {
        int p = l * 8 + j;                       // storage position 0..63
        w2v[j] = W2[(p & 3) * 16 + (p >> 2)];    // hidden unit index
    }
    float bb = b2[0];

    int gid = (int)((blockIdx.x * blockDim.x + threadIdx.x) >> 3);
    int ng  = (int)((gridDim.x * blockDim.x) >> 3);

    for (int e0 = gid * 4; e0 < nEdges; e0 += ng * 4) {
        if (e0 + 4 <= nEdges) {
            int4 r4 = *(const int4*)(row + e0);
            int4 c4 = *(const int4*)(col + e0);
            // issue all 8 gathers before any compute
            half8 a0 = *(const half8*)(UVh + ((unsigned)r4.x << 7) + l * 8);
            half8 b0 = *(const half8*)(UVh + ((unsigned)c4.x << 7) + 64 + l * 8);
            half8 a1 = *(const half8*)(UVh + ((unsigned)r4.y << 7) + l * 8);
            half8 b1 = *(const half8*)(UVh + ((unsigned)c4.y << 7) + 64 + l * 8);
            half8 a2 = *(const half8*)(UVh + ((unsigned)r4.z << 7) + l * 8);
            half8 b2v = *(const half8*)(UVh + ((unsigned)c4.z << 7) + 64 + l * 8);
            half8 a3 = *(const half8*)(UVh + ((unsigned)r4.w << 7) + l * 8);
            half8 b3 = *(const half8*)(UVh + ((unsigned)c4.w << 7) + 64 + l * 8);

            float p0 = 0.f, p1 = 0.f, p2 = 0.f, p3 = 0.f;
            #pragma unroll
            for (int j = 0; j < 8; ++j) {
                p0 = fmaf(fmaxf((float)a0[j] + (float)b0[j], 0.f), w2v[j], p0);
                p1 = fmaf(fmaxf((float)a1[j] + (float)b1[j], 0.f), w2v[j], p1);
                p2 = fmaf(fmaxf((float)a2[j] + (float)b2v[j], 0.f), w2v[j], p2);
                p3 = fmaf(fmaxf((float)a3[j] + (float)b3[j], 0.f), w2v[j], p3);
            }
            #pragma unroll
            for (int s = 1; s < 8; s <<= 1) {
                p0 += __shfl_xor(p0, s);
                p1 += __shfl_xor(p1, s);
                p2 += __shfl_xor(p2, s);
                p3 += __shfl_xor(p3, s);
            }
            if (l == 0) {
                fv4 o = {p0 + bb, p1 + bb, p2 + bb, p3 + bb};
                __builtin_nontemporal_store(o, (fv4*)(out + e0));
            }
        } else {
            for (int e = e0; e < nEdges; ++e) {
                int r = row[e];
                int c = col[e];
                half8 a = *(const half8*)(UVh + ((unsigned)r << 7) + l * 8);
                half8 b = *(const half8*)(UVh + ((unsigned)c << 7) + 64 + l * 8);
                float p = 0.f;
                #pragma unroll
                for (int j = 0; j < 8; ++j)
                    p = fmaf(fmaxf((float)a[j] + (float)b[j], 0.f), w2v[j], p);
                #pragma unroll
                for (int s = 1; s < 8; s <<= 1) p += __shfl_xor(p, s);
                if (l == 0) out[e] = p + bb;
            }
        }
    }
}

extern "C" void kernel_launch(void* const* d_in, const int* in_sizes, int n_in,
                              void* d_out, int out_size, void* d_ws, size_t ws_size,
                              hipStream_t stream) {
    const float* seq   = (const float*)d_in[0];
    const float* W_enc = (const float*)d_in[1];
    const float* b_enc = (const float*)d_in[2];
    const float* W1    = (const float*)d_in[3];
    const float* b1    = (const float*)d_in[4];
    const float* W2    = (const float*)d_in[5];
    const float* b2    = (const float*)d_in[6];
    const int*   row   = (const int*)d_in[7];
    const int*   col   = (const int*)d_in[8];
    float* out = (float*)d_out;

    int nNodes = in_sizes[0] / K_IN;     // 100000
    int nEdges = in_sizes[7];            // 1000000

    // workspace layout
    _Float16* UVh = (_Float16*)d_ws;                                   // 25.6 MB
    __hip_bfloat16* Wb = (__hip_bfloat16*)((char*)d_ws +
                         (size_t)nNodes * N_OUT * sizeof(_Float16));   // 32 KB
    float* bcat = (float*)((char*)Wb + N_OUT * K_IN * sizeof(__hip_bfloat16));

    prep_kernel<<<(N_OUT * K_IN + 255) / 256, 256, 0, stream>>>(
        W_enc, b_enc, W1, b1, Wb, bcat);

    int nblocksA = (nNodes + 127) / 128;             // 782
    node_proj_kernel<<<nblocksA, 512, 0, stream>>>(seq, Wb, bcat, UVh, nNodes);

    edge_kernel<<<2048, 256, 0, stream>>>(UVh, row, col, W2, b2, out, nEdges);
}